// Round 15
// baseline (145.066 us; speedup 1.0000x reference)
//
#include <hip/hip_runtime.h>
#include <hip/hip_bf16.h>

#define B_ 1024
#define IN_ 512
#define OUT_ 512
#define BTILE 64
#define OTILE 32
#define ITILE 8
#define KSPLIT 16
#define KCHUNK (IN_ / KSPLIT)          // 32 i's per block = one MFMA K
#define NCHUNKS (KCHUNK / ITILE)       // 4 staging chunks
#define P4STRIDE 128  // 32 o * 4 words; b128 writes even 8-phase (free); reads 2-way (free)
#define PLSTRIDE 32   // lw: [i][o], reads conflict-free
#define XSTRIDE 68    // BTILE + 4 pad; staging writes exactly 2-way (free)
#define ASTRIDE 40    // bf16 per sA/wB row = 80 B (16B-aligned); rows 2-way banks (free)

typedef float v2f   __attribute__((ext_vector_type(2)));
typedef float f32x4 __attribute__((ext_vector_type(4)));
typedef short s16x8 __attribute__((ext_vector_type(8)));   // 8 bf16 = 4 VGPRs
#define PKFMA(a, b, c) __builtin_elementwise_fma((v2f)(a), (v2f)(b), (v2f)(c))

__device__ __forceinline__ unsigned short f2bf(float f) {
    union { float f; unsigned int u; } v; v.f = f;
    unsigned int b = v.u + 0x7FFFu + ((v.u >> 16) & 1u);   // RNE
    return (unsigned short)(b >> 16);
}
__device__ __forceinline__ float fast_exp2(float x) {
#if __has_builtin(__builtin_amdgcn_exp2f)
    return __builtin_amdgcn_exp2f(x);
#else
    return __exp2f(x);
#endif
}
__device__ __forceinline__ float fast_log2(float x) {
#if __has_builtin(__builtin_amdgcn_logf)
    return __builtin_amdgcn_logf(x);
#else
    return __log2f(x);
#endif
}
__device__ __forceinline__ float fast_rcp(float x) {
#if __has_builtin(__builtin_amdgcn_rcpf)
    return __builtin_amdgcn_rcpf(x);
#else
    return 1.0f / x;
#endif
}

__global__ __launch_bounds__(256, 8) void chirplet_kernel(
    const float* __restrict__ x,
    const float* __restrict__ W,
    const float* __restrict__ Wc,
    const float* __restrict__ S,
    const float* __restrict__ T,
    const float* __restrict__ F,
    const float* __restrict__ bias,
    float* __restrict__ out)
{
    // R14 structure (chirplet on VALU, silu*W on matrix pipe, C-layouts aligned).
    // Delta: cos via deg-8 even minimax poly (z=rev-rndne(rev), Chebyshev-
    // economized, |eps|~1.5e-4) -> 8 cyc/group vs ~12 for v_cos_f32.
    __shared__ __align__(16) float p4_lds[ITILE * P4STRIDE];   // 4 KB {a,b',c2,d2}
    __shared__ __align__(16) float plw_lds[ITILE * PLSTRIDE];  // 1 KB log2|Wc|
    __shared__ __align__(16) float x_lds[ITILE * XSTRIDE];     // 2.125 KB [i][b]
    __shared__ __align__(16) unsigned short sA_lds[BTILE * ASTRIDE]; // 5 KB silu bf16 [b][k]
    __shared__ __align__(16) unsigned short wB_lds[OTILE * ASTRIDE]; // 2.5 KB W bf16 [o][k]

    const int tid  = threadIdx.x;
    const int wave = tid >> 6;
    const int lane = tid & 63;
    const int o0 = blockIdx.x * OTILE;
    const int b0 = blockIdx.y * BTILE;
    const int k0 = blockIdx.z * KCHUNK;

    const int oc = tid & 15;        // o col
    const int bq = tid >> 4;        // b quad: b = bq*4 + reg  (= MFMA C rows)

    const int xrow = tid >> 2;          // 0..63 (b)
    const int xq   = tid & 3;           // col pair 2*xq, 2*xq+1

    const int pol = tid & 31;           // o 0..31
    const int pi  = tid >> 5;           // i 0..7

    const float LOG2E = 1.4426950408889634f;
    const float GK    = 0.8493218002880191f;   // sqrt(0.5*log2(e))

    // cos(2*pi*z) ~= PC0 + w*(PC1 + w*(PC2 + w*(PC3 + w*PC4))), w=z^2, z in [-.5,.5]
    const v2f PC0 = {  0.99995994f,   0.99995994f  };
    const v2f PC1 = { -19.7311170f,  -19.7311170f  };
    const v2f PC2 = {  64.6764826f,   64.6764826f  };
    const v2f PC3 = { -82.4379372f,  -82.4379372f  };
    const v2f PC4 = {  45.7674064f,   45.7674064f  };

    v2f acc2[2][2] = {{{0.f,0.f},{0.f,0.f}},{{0.f,0.f},{0.f,0.f}}};

    for (int c = 0; c < NCHUNKS; ++c) {
        const int ib = k0 + c * ITILE;

        // ---- stage x tile: x fp32 -> x_lds[i][b]; silu bf16 -> sA_lds[b][k]
        {
            const float2 v = *(const float2*)(x + (size_t)(b0 + xrow) * IN_ + ib + xq * 2);
            const float xf[2] = { v.x, v.y };
            unsigned int packed = 0;
            #pragma unroll
            for (int j = 0; j < 2; ++j) {
                const int col = xq * 2 + j;
                float xv  = xf[j];
                float sig = fast_rcp(1.0f + fast_exp2(-xv * LOG2E));
                x_lds[col * XSTRIDE + xrow] = xv;
                packed |= (unsigned int)f2bf(xv * sig) << (16 * j);
            }
            *(unsigned int*)&sA_lds[xrow * ASTRIDE + c * 8 + xq * 2] = packed;
        }

        // ---- stage params (32 o x 8 i): chirplet coeffs + W bf16 for MFMA
        {
            const size_t go = (size_t)(o0 + pol) * IN_ + ib + pi;
            const float s  = S[go];
            const float t  = T[go];
            const float f  = F[go];
            const float w  = W[go];
            const float wc = Wc[go];
            const float rs = fast_rcp(s);
            const float a  = f * rs;                       // revolutions per x
            float4 p0;
            p0.x = a;
            p0.y = -a * t + (wc < 0.0f ? 0.5f : 0.0f);     // phase + sign(Wc)
            p0.z = rs * GK;
            p0.w = -t * rs * GK;
            *(float4*)&p4_lds[pi * P4STRIDE + pol * 4] = p0;
            plw_lds[pi * PLSTRIDE + pol] = fast_log2(fabsf(wc));
            wB_lds[pol * ASTRIDE + c * 8 + pi] = f2bf(w);
        }
        __syncthreads();

        // ---- compute: chirplet only; cos via packed poly, exp2 via HW trans
        #pragma unroll 4
        for (int i = 0; i < ITILE; ++i) {
            const float4 abcd[2] = {
                *(const float4*)&p4_lds[i * P4STRIDE + oc * 4],
                *(const float4*)&p4_lds[i * P4STRIDE + (oc + 16) * 4] };
            const float lw[2] = {
                plw_lds[i * PLSTRIDE + oc],
                plw_lds[i * PLSTRIDE + oc + 16] };
            const v2f* xp = (const v2f*)&x_lds[i * XSTRIDE + bq * 4];
            const v2f xk2[2] = { xp[0], xp[1] };
            #pragma unroll
            for (int o = 0; o < 2; ++o) {
                const v2f aa = { abcd[o].x, abcd[o].x };
                const v2f bb = { abcd[o].y, abcd[o].y };
                const v2f cc = { abcd[o].z, abcd[o].z };
                const v2f dd = { abcd[o].w, abcd[o].w };
                const v2f lwv = { lw[o], lw[o] };
                #pragma unroll
                for (int p = 0; p < 2; ++p) {
                    v2f rev = PKFMA(aa, xk2[p], bb);       // phase (revs)
                    v2f u   = PKFMA(cc, xk2[p], dd);       // GK*(x-t)/s
                    v2f arg = PKFMA(-u, u, lwv);           // lw - u^2
                    v2f zr;
                    zr.x = __builtin_rintf(rev.x);         // v_rndne_f32
                    zr.y = __builtin_rintf(rev.y);
                    const v2f z  = rev - zr;               // z in [-0.5, 0.5]
                    const v2f w2 = z * z;
                    const v2f co = PKFMA(w2,
                        PKFMA(w2, PKFMA(w2, PKFMA(w2, PC4, PC3), PC2), PC1), PC0);
                    v2f e;
                    e.x = fast_exp2(arg.x);
                    e.y = fast_exp2(arg.y);
                    acc2[o][p] = PKFMA(co, e, acc2[o][p]); // chirplet
                }
            }
        }
        __syncthreads();
    }

    // ---- silu*W via matrix pipe: D[b][o] = sum_k silu[b][k] * W[o][k]
    const int q8 = (lane >> 4) * 8;
    const s16x8 af  = *(const s16x8*)&sA_lds[(wave * 16 + (lane & 15)) * ASTRIDE + q8];
    const s16x8 bf0 = *(const s16x8*)&wB_lds[(lane & 15) * ASTRIDE + q8];
    const s16x8 bf1 = *(const s16x8*)&wB_lds[((lane & 15) + 16) * ASTRIDE + q8];
    const f32x4 mz = { 0.f, 0.f, 0.f, 0.f };
    const f32x4 m0 = __builtin_amdgcn_mfma_f32_16x16x32_bf16(af, bf0, mz, 0, 0, 0);
    const f32x4 m1 = __builtin_amdgcn_mfma_f32_16x16x32_bf16(af, bf1, mz, 0, 0, 0);

    // ---- epilogue: chirplet acc + MFMA acc (same C-layout) + bias, atomic add
    const float badd[2] = { (blockIdx.z == 0) ? bias[o0 + oc] : 0.0f,
                            (blockIdx.z == 0) ? bias[o0 + oc + 16] : 0.0f };
    #pragma unroll
    for (int o = 0; o < 2; ++o) {
        #pragma unroll
        for (int p = 0; p < 2; ++p) {
            #pragma unroll
            for (int j = 0; j < 2; ++j) {
                const int reg = p * 2 + j;
                const int b = b0 + bq * 4 + reg;
                float* dst = &out[(size_t)b * OUT_ + o0 + oc + o * 16];
                const float mm = (o == 0) ? m0[reg] : m1[reg];
                const float val = (j == 0 ? acc2[o][p].x : acc2[o][p].y) + mm + badd[o];
#if defined(__HIP_DEVICE_COMPILE__)
                unsafeAtomicAdd(dst, val);   // HW global_atomic_add_f32
#else
                atomicAdd(dst, val);
#endif
            }
        }
    }
}

extern "C" void kernel_launch(void* const* d_in, const int* in_sizes, int n_in,
                              void* d_out, int out_size, void* d_ws, size_t ws_size,
                              hipStream_t stream) {
    const float* x    = (const float*)d_in[0];
    const float* W    = (const float*)d_in[1];
    const float* Wc   = (const float*)d_in[2];
    const float* S    = (const float*)d_in[3];
    const float* T    = (const float*)d_in[4];
    const float* F    = (const float*)d_in[5];
    const float* bias = (const float*)d_in[6];
    float* out = (float*)d_out;

    // d_out is poisoned before every launch; atomics need zeroed destination
    hipMemsetAsync(out, 0, (size_t)out_size * sizeof(float), stream);

    dim3 grid(OUT_ / OTILE, B_ / BTILE, KSPLIT);   // 16 x 16 x 16 = 4096 blocks
    chirplet_kernel<<<grid, 256, 0, stream>>>(x, W, Wc, S, T, F, bias, out);
}

// Round 16
// 125.336 us; speedup vs baseline: 1.1574x; 1.1574x over previous
//
#include <hip/hip_runtime.h>
#include <hip/hip_bf16.h>

#define B_ 1024
#define IN_ 512
#define OUT_ 512
#define BTILE 64
#define OTILE 32
#define ITILE 16
#define KSPLIT 16
#define KCHUNK (IN_ / KSPLIT)          // 32 i's per block = one MFMA K
#define NCHUNKS (KCHUNK / ITILE)       // 2 staging chunks
#define P4STRIDE 128  // 32 o * 4 words; b128 writes even 8-phase (free); reads 2-way (free)
#define PLSTRIDE 32   // lw: [i][o], reads conflict-free
#define XSTRIDE 68    // BTILE + 4 pad; staging writes exactly 2-way (free)
#define ASTRIDE 40    // bf16 per sA/wB row = 80 B (16B-aligned rows); 2-way banks (free)

typedef float v2f   __attribute__((ext_vector_type(2)));
typedef float f32x4 __attribute__((ext_vector_type(4)));
typedef short s16x8 __attribute__((ext_vector_type(8)));   // 8 bf16 = 4 VGPRs
#define PKFMA(a, b, c) __builtin_elementwise_fma((v2f)(a), (v2f)(b), (v2f)(c))

__device__ __forceinline__ unsigned short f2bf(float f) {
    union { float f; unsigned int u; } v; v.f = f;
    unsigned int b = v.u + 0x7FFFu + ((v.u >> 16) & 1u);   // RNE
    return (unsigned short)(b >> 16);
}
__device__ __forceinline__ float fast_exp2(float x) {
#if __has_builtin(__builtin_amdgcn_exp2f)
    return __builtin_amdgcn_exp2f(x);
#else
    return __exp2f(x);
#endif
}
__device__ __forceinline__ float fast_log2(float x) {
#if __has_builtin(__builtin_amdgcn_logf)
    return __builtin_amdgcn_logf(x);
#else
    return __log2f(x);
#endif
}
__device__ __forceinline__ float fast_cos_rev(float x) {  // cos(2*pi*x), revolutions
#if __has_builtin(__builtin_amdgcn_cosf)
    return __builtin_amdgcn_cosf(x);   // ~12 busy-cyc/wave64 measured; poly is worse (R15)
#else
    return __cosf(x * 6.2831853071795864f);
#endif
}
__device__ __forceinline__ float fast_rcp(float x) {
#if __has_builtin(__builtin_amdgcn_rcpf)
    return __builtin_amdgcn_rcpf(x);
#else
    return 1.0f / x;
#endif
}

__global__ __launch_bounds__(256, 8) void chirplet_kernel(
    const float* __restrict__ x,
    const float* __restrict__ W,
    const float* __restrict__ Wc,
    const float* __restrict__ S,
    const float* __restrict__ T,
    const float* __restrict__ F,
    const float* __restrict__ bias,
    float* __restrict__ out)
{
    // R14 structure (chirplet on VALU, silu*W on matrix pipe). Delta: ITILE 16
    // -> 2 chunks -> 3 barriers/block (was 8). Inner loop identical to R14.
    __shared__ __align__(16) float p4_lds[ITILE * P4STRIDE];   // 8 KB {a,b',c2,d2}
    __shared__ __align__(16) float plw_lds[ITILE * PLSTRIDE];  // 2 KB log2|Wc|
    __shared__ __align__(16) float x_lds[ITILE * XSTRIDE];     // 4.25 KB [i][b]
    __shared__ __align__(16) unsigned short sA_lds[BTILE * ASTRIDE]; // 5 KB silu bf16 [b][k]
    __shared__ __align__(16) unsigned short wB_lds[OTILE * ASTRIDE]; // 2.5 KB W bf16 [o][k]

    const int tid  = threadIdx.x;
    const int wave = tid >> 6;
    const int lane = tid & 63;
    const int o0 = blockIdx.x * OTILE;
    const int b0 = blockIdx.y * BTILE;
    const int k0 = blockIdx.z * KCHUNK;

    const int oc = tid & 15;        // o col
    const int bq = tid >> 4;        // b quad: b = bq*4 + reg  (= MFMA C rows)

    const int xrow = tid >> 2;          // 0..63 (b)
    const int xq   = tid & 3;           // col quad: cols 4*xq .. 4*xq+3

    const int pol = tid & 31;           // o 0..31
    const int pi  = tid >> 5;           // i 0..7 (stages i=pi and i=pi+8)

    const float LOG2E = 1.4426950408889634f;
    const float GK    = 0.8493218002880191f;   // sqrt(0.5*log2(e))

    v2f acc2[2][2] = {{{0.f,0.f},{0.f,0.f}},{{0.f,0.f},{0.f,0.f}}};

    for (int c = 0; c < NCHUNKS; ++c) {
        const int ib = k0 + c * ITILE;

        // ---- stage x tile (64 b x 16 i): float4 load, silu, transpose; bf16 -> sA
        {
            const float4 v = *(const float4*)(x + (size_t)(b0 + xrow) * IN_ + ib + xq * 4);
            const float xf[4] = { v.x, v.y, v.z, v.w };
            unsigned long long packed = 0;
            #pragma unroll
            for (int j = 0; j < 4; ++j) {
                const int col = xq * 4 + j;
                float xv  = xf[j];
                float sig = fast_rcp(1.0f + fast_exp2(-xv * LOG2E));
                x_lds[col * XSTRIDE + xrow] = xv;   // banks exactly 2-way (free)
                packed |= (unsigned long long)f2bf(xv * sig) << (16 * j);
            }
            *(unsigned long long*)&sA_lds[xrow * ASTRIDE + c * 16 + xq * 4] = packed;
        }

        // ---- stage params (32 o x 16 i, 2 per thread): coeffs + W bf16 for MFMA
        #pragma unroll
        for (int h = 0; h < 2; ++h) {
            const int ii = pi + h * 8;
            const size_t go = (size_t)(o0 + pol) * IN_ + ib + ii;
            const float s  = S[go];
            const float t  = T[go];
            const float f  = F[go];
            const float w  = W[go];
            const float wc = Wc[go];
            const float rs = fast_rcp(s);
            const float a  = f * rs;                       // revolutions per x
            float4 p0;
            p0.x = a;
            p0.y = -a * t + (wc < 0.0f ? 0.5f : 0.0f);     // phase + sign(Wc)
            p0.z = rs * GK;
            p0.w = -t * rs * GK;
            *(float4*)&p4_lds[ii * P4STRIDE + pol * 4] = p0;
            plw_lds[ii * PLSTRIDE + pol] = fast_log2(fabsf(wc));
            wB_lds[pol * ASTRIDE + c * 16 + ii] = f2bf(w);
        }
        __syncthreads();

        // ---- compute: chirplet only (identical to R14 inner loop)
        #pragma unroll 4
        for (int i = 0; i < ITILE; ++i) {
            const float4 abcd[2] = {
                *(const float4*)&p4_lds[i * P4STRIDE + oc * 4],
                *(const float4*)&p4_lds[i * P4STRIDE + (oc + 16) * 4] };
            const float lw[2] = {
                plw_lds[i * PLSTRIDE + oc],
                plw_lds[i * PLSTRIDE + oc + 16] };
            const v2f* xp = (const v2f*)&x_lds[i * XSTRIDE + bq * 4];
            const v2f xk2[2] = { xp[0], xp[1] };
            #pragma unroll
            for (int o = 0; o < 2; ++o) {
                const v2f aa = { abcd[o].x, abcd[o].x };
                const v2f bb = { abcd[o].y, abcd[o].y };
                const v2f cc = { abcd[o].z, abcd[o].z };
                const v2f dd = { abcd[o].w, abcd[o].w };
                const v2f lwv = { lw[o], lw[o] };
                #pragma unroll
                for (int p = 0; p < 2; ++p) {
                    v2f rev = PKFMA(aa, xk2[p], bb);       // phase (revs)
                    v2f u   = PKFMA(cc, xk2[p], dd);       // GK*(x-t)/s
                    v2f arg = PKFMA(-u, u, lwv);           // lw - u^2
                    v2f co, e;
                    co.x = fast_cos_rev(rev.x);
                    co.y = fast_cos_rev(rev.y);
                    e.x  = fast_exp2(arg.x);
                    e.y  = fast_exp2(arg.y);
                    acc2[o][p] = PKFMA(co, e, acc2[o][p]); // chirplet
                }
            }
        }
        if (c < NCHUNKS - 1) __syncthreads();   // last chunk needs no trailing barrier
    }

    // ---- silu*W via matrix pipe: D[b][o] = sum_k silu[b][k] * W[o][k]
    const int q8 = (lane >> 4) * 8;
    const s16x8 af  = *(const s16x8*)&sA_lds[(wave * 16 + (lane & 15)) * ASTRIDE + q8];
    const s16x8 bf0 = *(const s16x8*)&wB_lds[(lane & 15) * ASTRIDE + q8];
    const s16x8 bf1 = *(const s16x8*)&wB_lds[((lane & 15) + 16) * ASTRIDE + q8];
    const f32x4 mz = { 0.f, 0.f, 0.f, 0.f };
    const f32x4 m0 = __builtin_amdgcn_mfma_f32_16x16x32_bf16(af, bf0, mz, 0, 0, 0);
    const f32x4 m1 = __builtin_amdgcn_mfma_f32_16x16x32_bf16(af, bf1, mz, 0, 0, 0);

    // ---- epilogue: chirplet acc + MFMA acc (same C-layout) + bias, atomic add
    const float badd[2] = { (blockIdx.z == 0) ? bias[o0 + oc] : 0.0f,
                            (blockIdx.z == 0) ? bias[o0 + oc + 16] : 0.0f };
    #pragma unroll
    for (int o = 0; o < 2; ++o) {
        #pragma unroll
        for (int p = 0; p < 2; ++p) {
            #pragma unroll
            for (int j = 0; j < 2; ++j) {
                const int reg = p * 2 + j;
                const int b = b0 + bq * 4 + reg;
                float* dst = &out[(size_t)b * OUT_ + o0 + oc + o * 16];
                const float mm = (o == 0) ? m0[reg] : m1[reg];
                const float val = (j == 0 ? acc2[o][p].x : acc2[o][p].y) + mm + badd[o];
#if defined(__HIP_DEVICE_COMPILE__)
                unsafeAtomicAdd(dst, val);   // HW global_atomic_add_f32
#else
                atomicAdd(dst, val);
#endif
            }
        }
    }
}

extern "C" void kernel_launch(void* const* d_in, const int* in_sizes, int n_in,
                              void* d_out, int out_size, void* d_ws, size_t ws_size,
                              hipStream_t stream) {
    const float* x    = (const float*)d_in[0];
    const float* W    = (const float*)d_in[1];
    const float* Wc   = (const float*)d_in[2];
    const float* S    = (const float*)d_in[3];
    const float* T    = (const float*)d_in[4];
    const float* F    = (const float*)d_in[5];
    const float* bias = (const float*)d_in[6];
    float* out = (float*)d_out;

    // d_out is poisoned before every launch; atomics need zeroed destination
    hipMemsetAsync(out, 0, (size_t)out_size * sizeof(float), stream);

    dim3 grid(OUT_ / OTILE, B_ / BTILE, KSPLIT);   // 16 x 16 x 16 = 4096 blocks
    chirplet_kernel<<<grid, 256, 0, stream>>>(x, W, Wc, S, T, F, bias, out);
}

// Round 17
// 125.069 us; speedup vs baseline: 1.1599x; 1.0021x over previous
//
#include <hip/hip_runtime.h>
#include <hip/hip_bf16.h>

#define B_ 1024
#define IN_ 512
#define OUT_ 512
#define BTILE 64
#define OTILE 32
#define ITILE 8
#define KSPLIT 16
#define KCHUNK (IN_ / KSPLIT)          // 32 i's per block = one MFMA K
#define NCHUNKS (KCHUNK / ITILE)       // 4 staging chunks
#define P4STRIDE 128  // 32 o * 4 words; b128 writes even 8-phase (free); reads 2-way (free)
#define PLSTRIDE 32   // lw: [i][o], reads conflict-free
#define XSTRIDE 68    // BTILE + 4 pad; staging writes exactly 2-way (free)
#define ASTRIDE 40    // bf16 per sA/wB row = 80 B (16B-aligned); rows 2-way banks (free)

typedef float v2f   __attribute__((ext_vector_type(2)));
typedef float f32x4 __attribute__((ext_vector_type(4)));
typedef short s16x8 __attribute__((ext_vector_type(8)));   // 8 bf16 = 4 VGPRs
#define PKFMA(a, b, c) __builtin_elementwise_fma((v2f)(a), (v2f)(b), (v2f)(c))

__device__ __forceinline__ unsigned short f2bf(float f) {
    union { float f; unsigned int u; } v; v.f = f;
    unsigned int b = v.u + 0x7FFFu + ((v.u >> 16) & 1u);   // RNE
    return (unsigned short)(b >> 16);
}
__device__ __forceinline__ float fast_exp2(float x) {
#if __has_builtin(__builtin_amdgcn_exp2f)
    return __builtin_amdgcn_exp2f(x);
#else
    return __exp2f(x);
#endif
}
__device__ __forceinline__ float fast_log2(float x) {
#if __has_builtin(__builtin_amdgcn_logf)
    return __builtin_amdgcn_logf(x);
#else
    return __log2f(x);
#endif
}
__device__ __forceinline__ float fast_cos_rev(float x) {  // cos(2*pi*x), revolutions
#if __has_builtin(__builtin_amdgcn_cosf)
    return __builtin_amdgcn_cosf(x);   // ~12 busy-cyc/wave64 measured (R6/R14 back-solves);
                                       // poly replacement measured WORSE (R15)
#else
    return __cosf(x * 6.2831853071795864f);
#endif
}
__device__ __forceinline__ float fast_rcp(float x) {
#if __has_builtin(__builtin_amdgcn_rcpf)
    return __builtin_amdgcn_rcpf(x);
#else
    return 1.0f / x;
#endif
}

__global__ __launch_bounds__(256, 8) void chirplet_kernel(
    const float* __restrict__ x,
    const float* __restrict__ W,
    const float* __restrict__ Wc,
    const float* __restrict__ S,
    const float* __restrict__ T,
    const float* __restrict__ F,
    const float* __restrict__ bias,
    float* __restrict__ out)
{
    // Best measured configuration (R14, 68.7 us):
    //  - chirplet path on VALU: 4 pk-fma + 4 trans per 2-elem unit (algebraic minimum;
    //    sign(Wc) folded into cos phase, |Wc| into exp2 offset)
    //  - silu*W GEMM on the otherwise-idle matrix pipe; accumulator mapping
    //    (oc=col, bq*4+reg=row) IS the MFMA 16x16 C/D layout -> register-to-register add
    //  - 15.4 KB LDS, 8 blocks/CU (wave cap), 16 blocks/CU queued (2x oversubscription)
    //  - fp32 atomics across 16 k-slices
    __shared__ __align__(16) float p4_lds[ITILE * P4STRIDE];   // 4 KB {a,b',c2,d2}
    __shared__ __align__(16) float plw_lds[ITILE * PLSTRIDE];  // 1 KB log2|Wc|
    __shared__ __align__(16) float x_lds[ITILE * XSTRIDE];     // 2.125 KB [i][b]
    __shared__ __align__(16) unsigned short sA_lds[BTILE * ASTRIDE]; // 5 KB silu bf16 [b][k]
    __shared__ __align__(16) unsigned short wB_lds[OTILE * ASTRIDE]; // 2.5 KB W bf16 [o][k]

    const int tid  = threadIdx.x;
    const int wave = tid >> 6;
    const int lane = tid & 63;
    const int o0 = blockIdx.x * OTILE;
    const int b0 = blockIdx.y * BTILE;
    const int k0 = blockIdx.z * KCHUNK;

    const int oc = tid & 15;        // o col
    const int bq = tid >> 4;        // b quad: b = bq*4 + reg  (= MFMA C rows)

    const int xrow = tid >> 2;          // 0..63 (b)
    const int xq   = tid & 3;           // col pair 2*xq, 2*xq+1

    const int pol = tid & 31;           // o 0..31
    const int pi  = tid >> 5;           // i 0..7

    const float LOG2E = 1.4426950408889634f;
    const float GK    = 0.8493218002880191f;   // sqrt(0.5*log2(e))

    v2f acc2[2][2] = {{{0.f,0.f},{0.f,0.f}},{{0.f,0.f},{0.f,0.f}}};

    for (int c = 0; c < NCHUNKS; ++c) {
        const int ib = k0 + c * ITILE;

        // ---- stage x tile: x fp32 -> x_lds[i][b]; silu bf16 -> sA_lds[b][k]
        {
            const float2 v = *(const float2*)(x + (size_t)(b0 + xrow) * IN_ + ib + xq * 2);
            const float xf[2] = { v.x, v.y };
            unsigned int packed = 0;
            #pragma unroll
            for (int j = 0; j < 2; ++j) {
                const int col = xq * 2 + j;
                float xv  = xf[j];
                float sig = fast_rcp(1.0f + fast_exp2(-xv * LOG2E));
                x_lds[col * XSTRIDE + xrow] = xv;
                packed |= (unsigned int)f2bf(xv * sig) << (16 * j);
            }
            *(unsigned int*)&sA_lds[xrow * ASTRIDE + c * 8 + xq * 2] = packed;
        }

        // ---- stage params (32 o x 8 i): chirplet coeffs + W bf16 for MFMA
        {
            const size_t go = (size_t)(o0 + pol) * IN_ + ib + pi;
            const float s  = S[go];
            const float t  = T[go];
            const float f  = F[go];
            const float w  = W[go];
            const float wc = Wc[go];
            const float rs = fast_rcp(s);
            const float a  = f * rs;                       // revolutions per x
            float4 p0;
            p0.x = a;
            p0.y = -a * t + (wc < 0.0f ? 0.5f : 0.0f);     // phase + sign(Wc)
            p0.z = rs * GK;
            p0.w = -t * rs * GK;
            *(float4*)&p4_lds[pi * P4STRIDE + pol * 4] = p0;
            plw_lds[pi * PLSTRIDE + pol] = fast_log2(fabsf(wc));
            wB_lds[pol * ASTRIDE + c * 8 + pi] = f2bf(w);
        }
        __syncthreads();

        // ---- compute: chirplet only (silu*W moved to MFMA)
        #pragma unroll 4
        for (int i = 0; i < ITILE; ++i) {
            const float4 abcd[2] = {
                *(const float4*)&p4_lds[i * P4STRIDE + oc * 4],
                *(const float4*)&p4_lds[i * P4STRIDE + (oc + 16) * 4] };
            const float lw[2] = {
                plw_lds[i * PLSTRIDE + oc],
                plw_lds[i * PLSTRIDE + oc + 16] };
            const v2f* xp = (const v2f*)&x_lds[i * XSTRIDE + bq * 4];
            const v2f xk2[2] = { xp[0], xp[1] };
            #pragma unroll
            for (int o = 0; o < 2; ++o) {
                const v2f aa = { abcd[o].x, abcd[o].x };
                const v2f bb = { abcd[o].y, abcd[o].y };
                const v2f cc = { abcd[o].z, abcd[o].z };
                const v2f dd = { abcd[o].w, abcd[o].w };
                const v2f lwv = { lw[o], lw[o] };
                #pragma unroll
                for (int p = 0; p < 2; ++p) {
                    v2f rev = PKFMA(aa, xk2[p], bb);       // phase (revs)
                    v2f u   = PKFMA(cc, xk2[p], dd);       // GK*(x-t)/s
                    v2f arg = PKFMA(-u, u, lwv);           // lw - u^2
                    v2f co, e;
                    co.x = fast_cos_rev(rev.x);
                    co.y = fast_cos_rev(rev.y);
                    e.x  = fast_exp2(arg.x);
                    e.y  = fast_exp2(arg.y);
                    acc2[o][p] = PKFMA(co, e, acc2[o][p]); // chirplet
                }
            }
        }
        __syncthreads();
    }

    // ---- silu*W via matrix pipe: D[b][o] = sum_k silu[b][k] * W[o][k]
    const int q8 = (lane >> 4) * 8;
    const s16x8 af  = *(const s16x8*)&sA_lds[(wave * 16 + (lane & 15)) * ASTRIDE + q8];
    const s16x8 bf0 = *(const s16x8*)&wB_lds[(lane & 15) * ASTRIDE + q8];
    const s16x8 bf1 = *(const s16x8*)&wB_lds[((lane & 15) + 16) * ASTRIDE + q8];
    const f32x4 mz = { 0.f, 0.f, 0.f, 0.f };
    const f32x4 m0 = __builtin_amdgcn_mfma_f32_16x16x32_bf16(af, bf0, mz, 0, 0, 0);
    const f32x4 m1 = __builtin_amdgcn_mfma_f32_16x16x32_bf16(af, bf1, mz, 0, 0, 0);

    // ---- epilogue: chirplet acc + MFMA acc (same C-layout) + bias, atomic add
    const float badd[2] = { (blockIdx.z == 0) ? bias[o0 + oc] : 0.0f,
                            (blockIdx.z == 0) ? bias[o0 + oc + 16] : 0.0f };
    #pragma unroll
    for (int o = 0; o < 2; ++o) {
        #pragma unroll
        for (int p = 0; p < 2; ++p) {
            #pragma unroll
            for (int j = 0; j < 2; ++j) {
                const int reg = p * 2 + j;
                const int b = b0 + bq * 4 + reg;
                float* dst = &out[(size_t)b * OUT_ + o0 + oc + o * 16];
                const float mm = (o == 0) ? m0[reg] : m1[reg];
                const float val = (j == 0 ? acc2[o][p].x : acc2[o][p].y) + mm + badd[o];
#if defined(__HIP_DEVICE_COMPILE__)
                unsafeAtomicAdd(dst, val);   // HW global_atomic_add_f32
#else
                atomicAdd(dst, val);
#endif
            }
        }
    }
}

extern "C" void kernel_launch(void* const* d_in, const int* in_sizes, int n_in,
                              void* d_out, int out_size, void* d_ws, size_t ws_size,
                              hipStream_t stream) {
    const float* x    = (const float*)d_in[0];
    const float* W    = (const float*)d_in[1];
    const float* Wc   = (const float*)d_in[2];
    const float* S    = (const float*)d_in[3];
    const float* T    = (const float*)d_in[4];
    const float* F    = (const float*)d_in[5];
    const float* bias = (const float*)d_in[6];
    float* out = (float*)d_out;

    // d_out is poisoned before every launch; atomics need zeroed destination
    hipMemsetAsync(out, 0, (size_t)out_size * sizeof(float), stream);

    dim3 grid(OUT_ / OTILE, B_ / BTILE, KSPLIT);   // 16 x 16 x 16 = 4096 blocks
    chirplet_kernel<<<grid, 256, 0, stream>>>(x, W, Wc, S, T, F, bias, out);
}